// Round 12
// baseline (155.981 us; speedup 1.0000x reference)
//
#include <hip/hip_runtime.h>
#include <hip/hip_bf16.h>
#include <math.h>

typedef unsigned int u32;
typedef unsigned short u16;
using f32x4  = __attribute__((ext_vector_type(4))) float;
using f32x16 = __attribute__((ext_vector_type(16))) float;
using bfrag  = __attribute__((ext_vector_type(8))) short;
using i32x4  = __attribute__((ext_vector_type(4))) int;
union FragU { uint4 u; bfrag f; };
union FragI { uint4 u; i32x4 f; };

#define HEADS 16
#define DH    64
#define NB    8
#define NN    1024
#define NC    1024
#define M_TOT 8192
#define O_QKV 3072
#define KDIM  1024
#define LOG2E 1.44269504088896340736f

// ---------- small helpers ----------
static __device__ __forceinline__ u16 f2bf(float f) {          // RNE float->bf16
  u32 u = __float_as_uint(f);
  return (u16)((u + 0x7fffu + ((u >> 16) & 1u)) >> 16);
}
static __device__ __forceinline__ u32 pk_bf16(float a, float b) {  // packed RNE pair
  __hip_bfloat162 h = __float22bfloat162_rn(make_float2(a, b));
  u32 r; __builtin_memcpy(&r, &h, 4); return r;
}

static __device__ __forceinline__ float wave_sum(float v) {
#pragma unroll
  for (int off = 32; off > 0; off >>= 1) v += __shfl_xor(v, off, 64);
  return v;
}
static __device__ __forceinline__ float wave_max(float v) {
#pragma unroll
  for (int off = 32; off > 0; off >>= 1) v = fmaxf(v, __shfl_xor(v, off, 64));
  return v;
}

static __device__ __forceinline__ f32x4 mfma16(FragU a, FragU b, f32x4 c) {
  return __builtin_amdgcn_mfma_f32_16x16x32_bf16(a.f, b.f, c, 0, 0, 0);
}
static __device__ __forceinline__ f32x16 mfma32(FragU a, FragU b, f32x16 c) {
  return __builtin_amdgcn_mfma_f32_32x32x16_bf16(a.f, b.f, c, 0, 0, 0);
}
static __device__ __forceinline__ i32x4 mfma16i(FragI a, FragI b, i32x4 c) {
  return __builtin_amdgcn_mfma_i32_16x16x64_i8(a.f, b.f, c, 0, 0, 0);
}

// half-exchange: a' = dest-half-selected {a,b} from lanes 0-31; b' = same from lanes 32-63
static __device__ __forceinline__ void pl32swap(u32& a, u32& b) {
#if __has_builtin(__builtin_amdgcn_permlane32_swap)
  using u32x2 = __attribute__((ext_vector_type(2))) unsigned int;
  u32x2 r = __builtin_amdgcn_permlane32_swap(a, b, false, false);
  a = r[0]; b = r[1];
#else
  asm volatile("v_permlane32_swap_b32 %0, %1" : "+v"(a), "+v"(b));
#endif
}

// Stage (P*BLK/8) rows x 128B per row: linear LDS dest, XOR-swizzled global source.
// Logical LDS slot [row][kc] holds G[row][kc ^ (row&7)]  (16B chunks, 8/row).
template<int P, int BLK>
static __device__ __forceinline__ void stage_rows(const char* g, int row_stride,
                                                  char* ldsb, int t) {
#pragma unroll
  for (int p = 0; p < P; ++p) {
    const int c = p * BLK + t;
    const int row = c >> 3, kc = c & 7;
    const char* gp = g + (size_t)row * row_stride + ((kc ^ (row & 7)) << 4);
    char* lp = ldsb + ((p * BLK + (t & ~63)) << 4);
    __builtin_amdgcn_global_load_lds((const __attribute__((address_space(1))) void*)gp,
                                     (__attribute__((address_space(3))) void*)lp, 16, 0, 0);
  }
}
// read logical [row][chunk] (chunk = 16B), applying the same XOR
static __device__ __forceinline__ uint4 ld_chunk(const char* base, int row, int chunk) {
  return *(const uint4*)(base + (((row << 3) + (chunk ^ (row & 7))) << 4));
}

// ---------- fused prep: LN stats (blocks 0..2047) + weight absmax partials ----------
__global__ __launch_bounds__(256) void prep_kernel(const float* __restrict__ x,
    const float* __restrict__ g, const float* __restrict__ b,
    const float4* __restrict__ wq, const float4* __restrict__ wo,
    float2* __restrict__ mrs, float* __restrict__ actp,
    float* __restrict__ wqp, float* __restrict__ wop)
{
  __shared__ float red[4];
  const int bid = blockIdx.x, t = threadIdx.x;
  if (bid < 2048) {                                    // LayerNorm stats, wave-per-row
    const int w = t >> 6, l = t & 63;
    const int row = (bid << 2) + w;
    const float4* xr = (const float4*)(x + (size_t)row * NC);
    float4 v[4];
#pragma unroll
    for (int j = 0; j < 4; ++j) v[j] = xr[l + (j << 6)];
    float s = 0.f;
#pragma unroll
    for (int j = 0; j < 4; ++j) s += (v[j].x + v[j].y) + (v[j].z + v[j].w);
    s = wave_sum(s);
    const float mu = s * (1.0f / NC);
    float ss = 0.f;
#pragma unroll
    for (int j = 0; j < 4; ++j) {
      const float dx = v[j].x - mu, dy = v[j].y - mu, dz = v[j].z - mu, dw = v[j].w - mu;
      ss += (dx * dx + dy * dy) + (dz * dz + dw * dw);
    }
    ss = wave_sum(ss);
    const float rstd = 1.0f / sqrtf(ss * (1.0f / NC) + 1e-5f);
    if (l == 0) mrs[row] = make_float2(mu, rstd);
    float am = 0.f;
#pragma unroll
    for (int j = 0; j < 4; ++j) {
      const float4 gv = ((const float4*)g)[l + (j << 6)];
      const float4 bv = ((const float4*)b)[l + (j << 6)];
      const float yx = (v[j].x - mu) * rstd * gv.x + bv.x;
      const float yy = (v[j].y - mu) * rstd * gv.y + bv.y;
      const float yz = (v[j].z - mu) * rstd * gv.z + bv.z;
      const float yw = (v[j].w - mu) * rstd * gv.w + bv.w;
      am = fmaxf(am, fmaxf(fmaxf(fabsf(yx), fabsf(yy)), fmaxf(fabsf(yz), fabsf(yw))));
    }
    am = wave_max(am);
    if (l == 0) red[w] = am;
    __syncthreads();
    if (t == 0) actp[bid] = fmaxf(fmaxf(red[0], red[1]), fmaxf(red[2], red[3]));
  } else {                                             // weight absmax partials
    const float4* p; int n4, lb, nb; float* o;
    if (bid < 2560) { p = wq; n4 = O_QKV * KDIM / 4; lb = bid - 2048; nb = 512; o = wqp + lb; }
    else            { p = wo; n4 = NC * KDIM / 4;    lb = bid - 2560; nb = 256; o = wop + lb; }
    float m = 0.f;
    for (int i = lb * 256 + t; i < n4; i += nb * 256) {
      float4 v = p[i];
      m = fmaxf(m, fmaxf(fmaxf(fabsf(v.x), fabsf(v.y)), fmaxf(fabsf(v.z), fabsf(v.w))));
    }
    m = wave_max(m);
    if ((t & 63) == 0) red[t >> 6] = m;
    __syncthreads();
    if (t == 0) *o = fmaxf(fmaxf(red[0], red[1]), fmaxf(red[2], red[3]));
  }
}

// ---------- final scalar reduce: 3 partial arrays -> scal[0..2] ----------
__global__ __launch_bounds__(256) void reduce3(const float* __restrict__ actp,
    const float* __restrict__ wqp, const float* __restrict__ wop,
    unsigned* __restrict__ scal)
{
  const int t = threadIdx.x;
  float a = 0.f, q = 0.f, o = 0.f;
#pragma unroll
  for (int k = 0; k < 8; ++k) a = fmaxf(a, actp[t + (k << 8)]);
  q = fmaxf(wqp[t], wqp[t + 256]);
  o = wop[t];
  a = wave_max(a); q = wave_max(q); o = wave_max(o);
  __shared__ float ra[4], rq[4], ro[4];
  if ((t & 63) == 0) { ra[t >> 6] = a; rq[t >> 6] = q; ro[t >> 6] = o; }
  __syncthreads();
  if (t == 0) {
    a = fmaxf(fmaxf(ra[0], ra[1]), fmaxf(ra[2], ra[3]));
    q = fmaxf(fmaxf(rq[0], rq[1]), fmaxf(rq[2], rq[3]));
    o = fmaxf(fmaxf(ro[0], ro[1]), fmaxf(ro[2], ro[3]));
    scal[0] = __float_as_uint(a == 0.f ? 1.f : a);
    scal[1] = __float_as_uint(q == 0.f ? 1.f : q);
    scal[2] = __float_as_uint(o == 0.f ? 1.f : o);
  }
}

// ---------- fused quant: x->i8 (blocks 0..8191), Wqkv->i8, Wout->bf16 ----------
__global__ __launch_bounds__(256) void quant_all(const float* __restrict__ x,
    const float* __restrict__ g, const float* __restrict__ b,
    const float2* __restrict__ mrs, const unsigned* __restrict__ scal,
    u32* __restrict__ xq, const float4* __restrict__ wq, u32* __restrict__ oq,
    const float4* __restrict__ wo, uint2* __restrict__ oo)
{
  const int bid = blockIdx.x, t = threadIdx.x;
  if (bid < 8192) {
    const long long row = bid;
    const float2 ms = mrs[row];
    const float s = __uint_as_float(scal[0]);
    const float4 v = ((const float4*)(x + row * NC))[t];
    const float4 gv = ((const float4*)g)[t];
    const float4 bv = ((const float4*)b)[t];
    float4 y;                                  // identical op sequence to prep -> same y
    y.x = (v.x - ms.x) * ms.y * gv.x + bv.x;
    y.y = (v.y - ms.x) * ms.y * gv.y + bv.y;
    y.z = (v.z - ms.x) * ms.y * gv.z + bv.z;
    y.w = (v.w - ms.x) * ms.y * gv.w + bv.w;
    const int ia = (int)rintf(y.x / s * 127.0f);   // reference op order: x / s * 127
    const int ib = (int)rintf(y.y / s * 127.0f);
    const int ic = (int)rintf(y.z / s * 127.0f);
    const int id = (int)rintf(y.w / s * 127.0f);
    xq[row * 256 + t] = (u32)(ia & 255) | ((u32)(ib & 255) << 8)
                      | ((u32)(ic & 255) << 16) | ((u32)(id & 255) << 24);
  } else if (bid < 8960) {
    const float s = __uint_as_float(scal[1]);
    const int base = (bid - 8192) << 10;
#pragma unroll
    for (int k = 0; k < 4; ++k) {
      const int i = base + (k << 8) + t;
      float4 v = wq[i];
      const int ia = (int)rintf(v.x / s * 127.0f);
      const int ib = (int)rintf(v.y / s * 127.0f);
      const int ic = (int)rintf(v.z / s * 127.0f);
      const int id = (int)rintf(v.w / s * 127.0f);
      oq[i] = (u32)(ia & 255) | ((u32)(ib & 255) << 8)
            | ((u32)(ic & 255) << 16) | ((u32)(id & 255) << 24);
    }
  } else {
    const float s = __uint_as_float(scal[2]);
    const int base = (bid - 8960) << 10;
#pragma unroll
    for (int k = 0; k < 4; ++k) {
      const int i = base + (k << 8) + t;
      float4 v = wo[i];
      uint2 o;
      o.x = pk_bf16(rintf(v.x / s * 127.0f), rintf(v.y / s * 127.0f));
      o.y = pk_bf16(rintf(v.z / s * 127.0f), rintf(v.w / s * 127.0f));
      oo[i] = o;
    }
  }
}

// ---------- QKV GEMM: int8 MFMA (exact); epilogue: q(scaled)/k bf16 + v^T bf16 ----------
__global__ __launch_bounds__(256) void gemm_qkv_mfma(const char* __restrict__ A,
    const char* __restrict__ B, const unsigned* __restrict__ scal,
    u16* __restrict__ qp, u16* __restrict__ kp, u16* __restrict__ vtp)
{
  __shared__ __align__(16) char lds[32768];
  char* As = lds;                    // 128 rows x 128 i8 (one K-tile of 128)
  char* Bs = lds + 16384;
  const int t = threadIdx.x, w = t >> 6, l = t & 63;
  const int lg = l >> 4, lc = l & 15;
  const int wm = (w >> 1) << 6, wn = (w & 1) << 6;
  i32x4 acc[4][4];
#pragma unroll
  for (int i = 0; i < 4; ++i)
#pragma unroll
    for (int j = 0; j < 4; ++j) acc[i][j] = 0;

  const char* gA = A + ((size_t)blockIdx.y << 7) * KDIM;
  const char* gB = B + ((size_t)blockIdx.x << 7) * KDIM;

  for (int k0 = 0; k0 < KDIM; k0 += 128) {           // 8 K-tiles
    stage_rows<4, 256>(gA + k0, KDIM, As, t);
    stage_rows<4, 256>(gB + k0, KDIM, Bs, t);
    __syncthreads();
#pragma unroll
    for (int ks = 0; ks < 2; ++ks) {                 // K=64 per MFMA
      FragI a[4], b[4];
#pragma unroll
      for (int mf = 0; mf < 4; ++mf) a[mf].u = ld_chunk(As, wm + (mf << 4) + lc, (ks << 2) + lg);
#pragma unroll
      for (int nf = 0; nf < 4; ++nf) b[nf].u = ld_chunk(Bs, wn + (nf << 4) + lc, (ks << 2) + lg);
      __builtin_amdgcn_s_setprio(1);
#pragma unroll
      for (int mf = 0; mf < 4; ++mf)
#pragma unroll
        for (int nf = 0; nf < 4; ++nf) acc[mf][nf] = mfma16i(a[mf], b[nf], acc[mf][nf]);
      __builtin_amdgcn_s_setprio(0);
    }
    __syncthreads();
  }

  const float sa = __uint_as_float(scal[0]), sw = __uint_as_float(scal[1]);
  const int which = blockIdx.x >> 3;                 // 0=q 1=k 2=v
  float sc = sa * sw / 16129.0f;
  if (which == 0) sc *= 0.125f * LOG2E;              // fold Dh^-0.5 AND log2(e) into q
  const int obase = ((blockIdx.x & 7) << 7) + wn;
  const int mbase = ((int)blockIdx.y << 7) + wm;

  if (which < 2) {
    u16* d_ = which ? kp : qp;
#pragma unroll
    for (int nf = 0; nf < 4; ++nf) {
      const int od = obase + (nf << 4) + lc;
      const int hh = od >> 6, dd = od & 63;
#pragma unroll
      for (int mf = 0; mf < 4; ++mf)
#pragma unroll
        for (int r = 0; r < 4; ++r) {
          const int tok = mbase + (mf << 4) + (lg << 2) + r;
          const size_t addr = ((size_t)((tok >> 10) * HEADS + hh) << 16)
                            + ((size_t)(tok & 1023) << 6) + dd;
          d_[addr] = f2bf((float)acc[mf][nf][r] * sc);
        }
    }
  } else {
#pragma unroll
    for (int nf = 0; nf < 4; ++nf) {
      const int od = obase + (nf << 4) + lc;
      const int hh = od >> 6, dd = od & 63;
#pragma unroll
      for (int mf = 0; mf < 4; ++mf) {
        const int tok0 = mbase + (mf << 4) + (lg << 2);
        uint2 hv;
        hv.x = pk_bf16((float)acc[mf][nf][0] * sc, (float)acc[mf][nf][1] * sc);
        hv.y = pk_bf16((float)acc[mf][nf][2] * sc, (float)acc[mf][nf][3] * sc);
        const size_t base = ((size_t)((tok0 >> 10) * HEADS + hh) << 16)
                          + ((size_t)dd << 10) + (tok0 & 1023);
        *(uint2*)(vtp + base) = hv;
      }
    }
  }
}

// ---------- flash attention: KVBLK=128, 4 waves x 64 q, K/V frags reused 2x ----------
__global__ __launch_bounds__(256, 2) void attn_mfma(
    const u16* __restrict__ qp, const u16* __restrict__ kp, const u16* __restrict__ vtp,
    u16* __restrict__ ohp)
{
  // per buffer (32KB): K 16K (128 rows x 128B) | V half0 8K | V half1 8K ; two buffers
  __shared__ __align__(16) char lds[65536];
  const int t = threadIdx.x, w = t >> 6, l = t & 63;
  const int l31 = l & 31, h = l >> 5;
  const int id = blockIdx.x;
  const int bh = ((id & 7) << 4) + ((id >> 3) & 15);   // q-blocks of a bh share an XCD
  const int qbase = ((id >> 7) << 8) + (w << 6);       // 256 q/block, 64 q/wave
  const size_t bhoff = (size_t)bh << 16;

  // two Q B-frags per wave: columns qbase+qg*32+l31, q pre-scaled by 0.125*log2e
  FragU qf[2][4];
#pragma unroll
  for (int qg = 0; qg < 2; ++qg)
#pragma unroll
    for (int ks = 0; ks < 4; ++ks)
      qf[qg][ks].u = *(const uint4*)(qp + bhoff
                     + ((size_t)(qbase + (qg << 5) + l31) << 6) + (ks << 4) + (h << 3));

  f32x16 oacc[2][2];
  oacc[0][0] = 0.f; oacc[0][1] = 0.f; oacc[1][0] = 0.f; oacc[1][1] = 0.f;
  float lpart[2] = {0.f, 0.f};

  stage_rows<4, 256>((const char*)(kp + bhoff), 128, lds, t);
  stage_rows<2, 256>((const char*)(vtp + bhoff), 2048, lds + 16384, t);
  stage_rows<2, 256>((const char*)(vtp + bhoff + 64), 2048, lds + 24576, t);
  __syncthreads();

  for (int kb = 0; kb < 8; ++kb) {
    char* cur = lds + ((kb & 1) << 15);
    if (kb < 7) {
      char* nxt = lds + (((kb + 1) & 1) << 15);
      const size_t kn = kb + 1;
      stage_rows<4, 256>((const char*)(kp + bhoff + (kn << 13)), 128, nxt, t);
      stage_rows<2, 256>((const char*)(vtp + bhoff + (kn << 7)), 2048, nxt + 16384, t);
      stage_rows<2, 256>((const char*)(vtp + bhoff + (kn << 7) + 64), 2048, nxt + 24576, t);
    }

    // four 32-key sub-phases; each K/V fragment feeds BOTH q-groups (2x LDS reuse)
#pragma unroll
    for (int sub = 0; sub < 4; ++sub) {
      f32x16 s0 = 0.f, s1 = 0.f;
#pragma unroll
      for (int ks = 0; ks < 4; ++ks) {
        FragU kf;
        kf.u = ld_chunk(cur, (sub << 5) + l31, (ks << 1) + h);
        __builtin_amdgcn_s_setprio(1);
        s0 = mfma32(kf, qf[0][ks], s0);
        s1 = mfma32(kf, qf[1][ks], s1);
        __builtin_amdgcn_s_setprio(0);
      }

      u32 W0[8], W1[8];
      float ls0 = 0.f, ls1 = 0.f;
#pragma unroll
      for (int j = 0; j < 8; ++j) {
        const float a0 = __builtin_amdgcn_exp2f(s0[2 * j]);
        const float b0 = __builtin_amdgcn_exp2f(s0[2 * j + 1]);
        const float a1 = __builtin_amdgcn_exp2f(s1[2 * j]);
        const float b1 = __builtin_amdgcn_exp2f(s1[2 * j + 1]);
        ls0 += a0 + b0; ls1 += a1 + b1;
        W0[j] = pk_bf16(a0, b0);
        W1[j] = pk_bf16(a1, b1);
      }
      lpart[0] += ls0; lpart[1] += ls1;

      FragU pf0[2], pf1[2];
#pragma unroll
      for (int kk = 0; kk < 2; ++kk) {
        u32 a0 = W0[4 * kk + 0], b0 = W0[4 * kk + 2];
        u32 a1 = W0[4 * kk + 1], b1 = W0[4 * kk + 3];
        pl32swap(a0, b0); pl32swap(a1, b1);
        pf0[kk].u = make_uint4(a0, a1, b0, b1);
        u32 c0 = W1[4 * kk + 0], d0 = W1[4 * kk + 2];
        u32 c1 = W1[4 * kk + 1], d1 = W1[4 * kk + 3];
        pl32swap(c0, d0); pl32swap(c1, d1);
        pf1[kk].u = make_uint4(c0, c1, d0, d1);
      }

      char* Vh = cur + 16384 + ((sub >> 1) << 13);
#pragma unroll
      for (int ks = 0; ks < 2; ++ks)
#pragma unroll
        for (int dt = 0; dt < 2; ++dt) {
          FragU vf;
          vf.u = ld_chunk(Vh, (dt << 5) + l31, ((sub & 1) << 2) + (ks << 1) + h);
          __builtin_amdgcn_s_setprio(1);
          oacc[0][dt] = mfma32(vf, pf0[ks], oacc[0][dt]);
          oacc[1][dt] = mfma32(vf, pf1[ks], oacc[1][dt]);
          __builtin_amdgcn_s_setprio(0);
        }
    }
    __syncthreads();   // buffer swap; drains prefetch (had the whole compute phase)
  }

  const int b = bh >> 4, hd_ = bh & 15;
#pragma unroll
  for (int qg = 0; qg < 2; ++qg) {
    lpart[qg] += __shfl_xor(lpart[qg], 32, 64);
    const float invl = 1.0f / lpart[qg];
    const size_t orow = (size_t)b * NN + qbase + (qg << 5) + l31;
    u16* ohb = ohp + (orow << 10) + (hd_ << 6);
#pragma unroll
    for (int dt = 0; dt < 2; ++dt)
#pragma unroll
      for (int rg = 0; rg < 4; ++rg) {
        const int d0 = (dt << 5) + (rg << 3) + (h << 2);
        const float v0 = oacc[qg][dt][4 * rg + 0] * invl, v1 = oacc[qg][dt][4 * rg + 1] * invl;
        const float v2 = oacc[qg][dt][4 * rg + 2] * invl, v3 = oacc[qg][dt][4 * rg + 3] * invl;
        uint2 hv;
        hv.x = (u32)f2bf(v0) | ((u32)f2bf(v1) << 16);
        hv.y = (u32)f2bf(v2) | ((u32)f2bf(v3) << 16);
        *(uint2*)(ohb + d0) = hv;
      }
  }
}

// ---------- out projection: o(bf16) x W_codes(bf16), + bias ----------
__global__ __launch_bounds__(256) void gemm_out_mfma(const u16* __restrict__ Ah,
    const u16* __restrict__ B, const unsigned* __restrict__ scal,
    const float* __restrict__ bias, float* __restrict__ out)
{
  __shared__ __align__(16) char lds[32768];
  char* Ahs = lds;
  char* Bs  = lds + 16384;
  const int t = threadIdx.x, w = t >> 6, l = t & 63;
  const int lg = l >> 4, lc = l & 15;
  const int wm = (w >> 1) << 6, wn = (w & 1) << 6;
  f32x4 acc[4][4];
#pragma unroll
  for (int i = 0; i < 4; ++i)
#pragma unroll
    for (int j = 0; j < 4; ++j) acc[i][j] = 0.f;

  const char* gAh = (const char*)Ah + ((size_t)blockIdx.y << 7) * 2048;
  const char* gB  = (const char*)B  + ((size_t)blockIdx.x << 7) * 2048;

  for (int k0 = 0; k0 < KDIM; k0 += 64) {
    stage_rows<4, 256>(gAh + k0 * 2, 2048, Ahs, t);
    stage_rows<4, 256>(gB  + k0 * 2, 2048, Bs,  t);
    __syncthreads();
#pragma unroll
    for (int ks = 0; ks < 2; ++ks) {
      FragU a[4], b[4];
#pragma unroll
      for (int mf = 0; mf < 4; ++mf) a[mf].u = ld_chunk(Ahs, wm + (mf << 4) + lc, (ks << 2) + lg);
#pragma unroll
      for (int nf = 0; nf < 4; ++nf) b[nf].u = ld_chunk(Bs, wn + (nf << 4) + lc, (ks << 2) + lg);
      __builtin_amdgcn_s_setprio(1);
#pragma unroll
      for (int mf = 0; mf < 4; ++mf)
#pragma unroll
        for (int nf = 0; nf < 4; ++nf) acc[mf][nf] = mfma16(a[mf], b[nf], acc[mf][nf]);
      __builtin_amdgcn_s_setprio(0);
    }
    __syncthreads();
  }

  const float sc = __uint_as_float(scal[2]) / 127.0f;
  const int cb = ((int)blockIdx.x << 7) + wn;
  const int mb = ((int)blockIdx.y << 7) + wm;
#pragma unroll
  for (int nf = 0; nf < 4; ++nf) {
    const int col = cb + (nf << 4) + lc;
    const float bv = bias[col];
#pragma unroll
    for (int mf = 0; mf < 4; ++mf)
#pragma unroll
      for (int r = 0; r < 4; ++r) {
        const int row = mb + (mf << 4) + (lg << 2) + r;
        out[(size_t)row * NC + col] = acc[mf][nf][r] * sc + bv;
      }
  }
}

__global__ void ws_fail_kernel(float* out) { out[0] = 1.0e6f; }

// ---------- launcher ----------
extern "C" void kernel_launch(void* const* d_in, const int* in_sizes, int n_in,
                              void* d_out, int out_size, void* d_ws, size_t ws_size,
                              hipStream_t stream) {
  const float* x     = (const float*)d_in[0];
  const float* gamma = (const float*)d_in[1];
  const float* beta  = (const float*)d_in[2];
  const float* Wqkv  = (const float*)d_in[3];
  const float* Wout  = (const float*)d_in[4];
  const float* bout  = (const float*)d_in[5];
  float* out = (float*)d_out;

  char* ws = (char*)d_ws;
  unsigned* scal = (unsigned*)ws;          // [0]=s_act [1]=s_wqkv [2]=s_wout
  size_t off = 256;
  float* actp = (float*)(ws + off); off += 2048 * 4;
  float* wqp  = (float*)(ws + off); off += 512 * 4;
  float* wop  = (float*)(ws + off); off += 256 * 4;
  off = (off + 255) & ~(size_t)255;
  float2* mrs = (float2*)(ws + off); off += (size_t)M_TOT * 8;
  char* xq  = ws + off; off += (size_t)M_TOT * KDIM;       // i8 codes
  char* wqi = ws + off; off += (size_t)O_QKV * KDIM;       // i8 codes
  u16* woi = (u16*)(ws + off); off += (size_t)NC * KDIM * 2;  // bf16 codes
  u16* qb  = (u16*)(ws + off); off += 16777216;
  u16* kb  = (u16*)(ws + off); off += 16777216;
  u16* vtb = (u16*)(ws + off); off += 16777216;
  u16* oh  = (u16*)(ws + off); off += 16777216;
  if (ws_size < off) { ws_fail_kernel<<<1, 1, 0, stream>>>(out); return; }

  prep_kernel<<<2816, 256, 0, stream>>>(x, gamma, beta, (const float4*)Wqkv,
                                        (const float4*)Wout, mrs, actp, wqp, wop);
  reduce3<<<1, 256, 0, stream>>>(actp, wqp, wop, scal);
  quant_all<<<9216, 256, 0, stream>>>(x, gamma, beta, mrs, scal, (u32*)xq,
                                      (const float4*)Wqkv, (u32*)wqi,
                                      (const float4*)Wout, (uint2*)woi);

  dim3 g1(O_QKV / 128, M_TOT / 128);
  gemm_qkv_mfma<<<g1, 256, 0, stream>>>(xq, wqi, scal, qb, kb, vtb);

  attn_mfma<<<512, 256, 0, stream>>>(qb, kb, vtb, oh);

  dim3 g3(NC / 128, M_TOT / 128);
  gemm_out_mfma<<<g3, 256, 0, stream>>>(oh, woi, scal, bout, out);
}

// Round 13
// 139.136 us; speedup vs baseline: 1.1211x; 1.1211x over previous
//
#include <hip/hip_runtime.h>
#include <hip/hip_bf16.h>
#include <math.h>

typedef unsigned int u32;
typedef unsigned short u16;
using f32x4  = __attribute__((ext_vector_type(4))) float;
using f32x16 = __attribute__((ext_vector_type(16))) float;
using bfrag  = __attribute__((ext_vector_type(8))) short;
using i32x4  = __attribute__((ext_vector_type(4))) int;
union FragU { uint4 u; bfrag f; };
union FragI { uint4 u; i32x4 f; };

#define HEADS 16
#define DH    64
#define NB    8
#define NN    1024
#define NC    1024
#define M_TOT 8192
#define O_QKV 3072
#define KDIM  1024
#define LOG2E 1.44269504088896340736f

// ---------- small helpers ----------
static __device__ __forceinline__ u16 f2bf(float f) {          // RNE float->bf16
  u32 u = __float_as_uint(f);
  return (u16)((u + 0x7fffu + ((u >> 16) & 1u)) >> 16);
}
static __device__ __forceinline__ u32 pk_bf16(float a, float b) {  // packed RNE pair
  __hip_bfloat162 h = __float22bfloat162_rn(make_float2(a, b));
  u32 r; __builtin_memcpy(&r, &h, 4); return r;
}

static __device__ __forceinline__ float wave_sum(float v) {
#pragma unroll
  for (int off = 32; off > 0; off >>= 1) v += __shfl_xor(v, off, 64);
  return v;
}
static __device__ __forceinline__ float wave_max(float v) {
#pragma unroll
  for (int off = 32; off > 0; off >>= 1) v = fmaxf(v, __shfl_xor(v, off, 64));
  return v;
}

static __device__ __forceinline__ f32x4 mfma16(FragU a, FragU b, f32x4 c) {
  return __builtin_amdgcn_mfma_f32_16x16x32_bf16(a.f, b.f, c, 0, 0, 0);
}
static __device__ __forceinline__ f32x16 mfma32(FragU a, FragU b, f32x16 c) {
  return __builtin_amdgcn_mfma_f32_32x32x16_bf16(a.f, b.f, c, 0, 0, 0);
}
static __device__ __forceinline__ i32x4 mfma16i(FragI a, FragI b, i32x4 c) {
  return __builtin_amdgcn_mfma_i32_16x16x64_i8(a.f, b.f, c, 0, 0, 0);
}

// half-exchange: a' = dest-half-selected {a,b} from lanes 0-31; b' = same from lanes 32-63
static __device__ __forceinline__ void pl32swap(u32& a, u32& b) {
#if __has_builtin(__builtin_amdgcn_permlane32_swap)
  using u32x2 = __attribute__((ext_vector_type(2))) unsigned int;
  u32x2 r = __builtin_amdgcn_permlane32_swap(a, b, false, false);
  a = r[0]; b = r[1];
#else
  asm volatile("v_permlane32_swap_b32 %0, %1" : "+v"(a), "+v"(b));
#endif
}

// Stage (P*BLK/8) rows x 128B per row: linear LDS dest, XOR-swizzled global source.
// Logical LDS slot [row][kc] holds G[row][kc ^ (row&7)]  (16B chunks, 8/row).
template<int P, int BLK>
static __device__ __forceinline__ void stage_rows(const char* g, int row_stride,
                                                  char* ldsb, int t) {
#pragma unroll
  for (int p = 0; p < P; ++p) {
    const int c = p * BLK + t;
    const int row = c >> 3, kc = c & 7;
    const char* gp = g + (size_t)row * row_stride + ((kc ^ (row & 7)) << 4);
    char* lp = ldsb + ((p * BLK + (t & ~63)) << 4);
    __builtin_amdgcn_global_load_lds((const __attribute__((address_space(1))) void*)gp,
                                     (__attribute__((address_space(3))) void*)lp, 16, 0, 0);
  }
}
// read logical [row][chunk] (chunk = 16B), applying the same XOR
static __device__ __forceinline__ uint4 ld_chunk(const char* base, int row, int chunk) {
  return *(const uint4*)(base + (((row << 3) + (chunk ^ (row & 7))) << 4));
}

// ---------- fused prep: LN stats (blocks 0..2047) + weight absmax partials ----------
__global__ __launch_bounds__(256) void prep_kernel(const float* __restrict__ x,
    const float* __restrict__ g, const float* __restrict__ b,
    const float4* __restrict__ wq, const float4* __restrict__ wo,
    float2* __restrict__ mrs, float* __restrict__ actp,
    float* __restrict__ wqp, float* __restrict__ wop)
{
  __shared__ float red[4];
  const int bid = blockIdx.x, t = threadIdx.x;
  if (bid < 2048) {                                    // LayerNorm stats, wave-per-row
    const int w = t >> 6, l = t & 63;
    const int row = (bid << 2) + w;
    const float4* xr = (const float4*)(x + (size_t)row * NC);
    float4 v[4];
#pragma unroll
    for (int j = 0; j < 4; ++j) v[j] = xr[l + (j << 6)];
    float s = 0.f;
#pragma unroll
    for (int j = 0; j < 4; ++j) s += (v[j].x + v[j].y) + (v[j].z + v[j].w);
    s = wave_sum(s);
    const float mu = s * (1.0f / NC);
    float ss = 0.f;
#pragma unroll
    for (int j = 0; j < 4; ++j) {
      const float dx = v[j].x - mu, dy = v[j].y - mu, dz = v[j].z - mu, dw = v[j].w - mu;
      ss += (dx * dx + dy * dy) + (dz * dz + dw * dw);
    }
    ss = wave_sum(ss);
    const float rstd = 1.0f / sqrtf(ss * (1.0f / NC) + 1e-5f);
    if (l == 0) mrs[row] = make_float2(mu, rstd);
    float am = 0.f;
#pragma unroll
    for (int j = 0; j < 4; ++j) {
      const float4 gv = ((const float4*)g)[l + (j << 6)];
      const float4 bv = ((const float4*)b)[l + (j << 6)];
      const float yx = (v[j].x - mu) * rstd * gv.x + bv.x;
      const float yy = (v[j].y - mu) * rstd * gv.y + bv.y;
      const float yz = (v[j].z - mu) * rstd * gv.z + bv.z;
      const float yw = (v[j].w - mu) * rstd * gv.w + bv.w;
      am = fmaxf(am, fmaxf(fmaxf(fabsf(yx), fabsf(yy)), fmaxf(fabsf(yz), fabsf(yw))));
    }
    am = wave_max(am);
    if (l == 0) red[w] = am;
    __syncthreads();
    if (t == 0) actp[bid] = fmaxf(fmaxf(red[0], red[1]), fmaxf(red[2], red[3]));
  } else {                                             // weight absmax partials
    const float4* p; int n4, lb, nb; float* o;
    if (bid < 2560) { p = wq; n4 = O_QKV * KDIM / 4; lb = bid - 2048; nb = 512; o = wqp + lb; }
    else            { p = wo; n4 = NC * KDIM / 4;    lb = bid - 2560; nb = 256; o = wop + lb; }
    float m = 0.f;
    for (int i = lb * 256 + t; i < n4; i += nb * 256) {
      float4 v = p[i];
      m = fmaxf(m, fmaxf(fmaxf(fabsf(v.x), fabsf(v.y)), fmaxf(fabsf(v.z), fabsf(v.w))));
    }
    m = wave_max(m);
    if ((t & 63) == 0) red[t >> 6] = m;
    __syncthreads();
    if (t == 0) *o = fmaxf(fmaxf(red[0], red[1]), fmaxf(red[2], red[3]));
  }
}

// ---------- final scalar reduce: 3 partial arrays -> scal[0..2] ----------
__global__ __launch_bounds__(256) void reduce3(const float* __restrict__ actp,
    const float* __restrict__ wqp, const float* __restrict__ wop,
    unsigned* __restrict__ scal)
{
  const int t = threadIdx.x;
  float a = 0.f, q = 0.f, o = 0.f;
#pragma unroll
  for (int k = 0; k < 8; ++k) a = fmaxf(a, actp[t + (k << 8)]);
  q = fmaxf(wqp[t], wqp[t + 256]);
  o = wop[t];
  a = wave_max(a); q = wave_max(q); o = wave_max(o);
  __shared__ float ra[4], rq[4], ro[4];
  if ((t & 63) == 0) { ra[t >> 6] = a; rq[t >> 6] = q; ro[t >> 6] = o; }
  __syncthreads();
  if (t == 0) {
    a = fmaxf(fmaxf(ra[0], ra[1]), fmaxf(ra[2], ra[3]));
    q = fmaxf(fmaxf(rq[0], rq[1]), fmaxf(rq[2], rq[3]));
    o = fmaxf(fmaxf(ro[0], ro[1]), fmaxf(ro[2], ro[3]));
    scal[0] = __float_as_uint(a == 0.f ? 1.f : a);
    scal[1] = __float_as_uint(q == 0.f ? 1.f : q);
    scal[2] = __float_as_uint(o == 0.f ? 1.f : o);
  }
}

// ---------- fused quant: x->i8 (blocks 0..8191), Wqkv->i8, Wout->bf16 ----------
__global__ __launch_bounds__(256) void quant_all(const float* __restrict__ x,
    const float* __restrict__ g, const float* __restrict__ b,
    const float2* __restrict__ mrs, const unsigned* __restrict__ scal,
    u32* __restrict__ xq, const float4* __restrict__ wq, u32* __restrict__ oq,
    const float4* __restrict__ wo, uint2* __restrict__ oo)
{
  const int bid = blockIdx.x, t = threadIdx.x;
  if (bid < 8192) {
    const long long row = bid;
    const float2 ms = mrs[row];
    const float s = __uint_as_float(scal[0]);
    const float4 v = ((const float4*)(x + row * NC))[t];
    const float4 gv = ((const float4*)g)[t];
    const float4 bv = ((const float4*)b)[t];
    float4 y;                                  // identical op sequence to prep -> same y
    y.x = (v.x - ms.x) * ms.y * gv.x + bv.x;
    y.y = (v.y - ms.x) * ms.y * gv.y + bv.y;
    y.z = (v.z - ms.x) * ms.y * gv.z + bv.z;
    y.w = (v.w - ms.x) * ms.y * gv.w + bv.w;
    const int ia = (int)rintf(y.x / s * 127.0f);   // reference op order: x / s * 127
    const int ib = (int)rintf(y.y / s * 127.0f);
    const int ic = (int)rintf(y.z / s * 127.0f);
    const int id = (int)rintf(y.w / s * 127.0f);
    xq[row * 256 + t] = (u32)(ia & 255) | ((u32)(ib & 255) << 8)
                      | ((u32)(ic & 255) << 16) | ((u32)(id & 255) << 24);
  } else if (bid < 8960) {
    const float s = __uint_as_float(scal[1]);
    const int base = (bid - 8192) << 10;
#pragma unroll
    for (int k = 0; k < 4; ++k) {
      const int i = base + (k << 8) + t;
      float4 v = wq[i];
      const int ia = (int)rintf(v.x / s * 127.0f);
      const int ib = (int)rintf(v.y / s * 127.0f);
      const int ic = (int)rintf(v.z / s * 127.0f);
      const int id = (int)rintf(v.w / s * 127.0f);
      oq[i] = (u32)(ia & 255) | ((u32)(ib & 255) << 8)
            | ((u32)(ic & 255) << 16) | ((u32)(id & 255) << 24);
    }
  } else {
    const float s = __uint_as_float(scal[2]);
    const int base = (bid - 8960) << 10;
#pragma unroll
    for (int k = 0; k < 4; ++k) {
      const int i = base + (k << 8) + t;
      float4 v = wo[i];
      uint2 o;
      o.x = pk_bf16(rintf(v.x / s * 127.0f), rintf(v.y / s * 127.0f));
      o.y = pk_bf16(rintf(v.z / s * 127.0f), rintf(v.w / s * 127.0f));
      oo[i] = o;
    }
  }
}

// ---------- QKV GEMM: int8 MFMA (exact); epilogue: q(scaled)/k bf16 + v^T bf16 ----------
__global__ __launch_bounds__(256) void gemm_qkv_mfma(const char* __restrict__ A,
    const char* __restrict__ B, const unsigned* __restrict__ scal,
    u16* __restrict__ qp, u16* __restrict__ kp, u16* __restrict__ vtp)
{
  __shared__ __align__(16) char lds[32768];
  char* As = lds;                    // 128 rows x 128 i8 (one K-tile of 128)
  char* Bs = lds + 16384;
  const int t = threadIdx.x, w = t >> 6, l = t & 63;
  const int lg = l >> 4, lc = l & 15;
  const int wm = (w >> 1) << 6, wn = (w & 1) << 6;
  i32x4 acc[4][4];
#pragma unroll
  for (int i = 0; i < 4; ++i)
#pragma unroll
    for (int j = 0; j < 4; ++j) acc[i][j] = 0;

  const char* gA = A + ((size_t)blockIdx.y << 7) * KDIM;
  const char* gB = B + ((size_t)blockIdx.x << 7) * KDIM;

  for (int k0 = 0; k0 < KDIM; k0 += 128) {           // 8 K-tiles
    stage_rows<4, 256>(gA + k0, KDIM, As, t);
    stage_rows<4, 256>(gB + k0, KDIM, Bs, t);
    __syncthreads();
#pragma unroll
    for (int ks = 0; ks < 2; ++ks) {                 // K=64 per MFMA
      FragI a[4], b[4];
#pragma unroll
      for (int mf = 0; mf < 4; ++mf) a[mf].u = ld_chunk(As, wm + (mf << 4) + lc, (ks << 2) + lg);
#pragma unroll
      for (int nf = 0; nf < 4; ++nf) b[nf].u = ld_chunk(Bs, wn + (nf << 4) + lc, (ks << 2) + lg);
      __builtin_amdgcn_s_setprio(1);
#pragma unroll
      for (int mf = 0; mf < 4; ++mf)
#pragma unroll
        for (int nf = 0; nf < 4; ++nf) acc[mf][nf] = mfma16i(a[mf], b[nf], acc[mf][nf]);
      __builtin_amdgcn_s_setprio(0);
    }
    __syncthreads();
  }

  const float sa = __uint_as_float(scal[0]), sw = __uint_as_float(scal[1]);
  const int which = blockIdx.x >> 3;                 // 0=q 1=k 2=v
  float sc = sa * sw / 16129.0f;
  if (which == 0) sc *= 0.125f * LOG2E;              // fold Dh^-0.5 AND log2(e) into q
  const int obase = ((blockIdx.x & 7) << 7) + wn;
  const int mbase = ((int)blockIdx.y << 7) + wm;

  if (which < 2) {
    u16* d_ = which ? kp : qp;
#pragma unroll
    for (int nf = 0; nf < 4; ++nf) {
      const int od = obase + (nf << 4) + lc;
      const int hh = od >> 6, dd = od & 63;
#pragma unroll
      for (int mf = 0; mf < 4; ++mf)
#pragma unroll
        for (int r = 0; r < 4; ++r) {
          const int tok = mbase + (mf << 4) + (lg << 2) + r;
          const size_t addr = ((size_t)((tok >> 10) * HEADS + hh) << 16)
                            + ((size_t)(tok & 1023) << 6) + dd;
          d_[addr] = f2bf((float)acc[mf][nf][r] * sc);
        }
    }
  } else {
#pragma unroll
    for (int nf = 0; nf < 4; ++nf) {
      const int od = obase + (nf << 4) + lc;
      const int hh = od >> 6, dd = od & 63;
#pragma unroll
      for (int mf = 0; mf < 4; ++mf) {
        const int tok0 = mbase + (mf << 4) + (lg << 2);
        uint2 hv;
        hv.x = pk_bf16((float)acc[mf][nf][0] * sc, (float)acc[mf][nf][1] * sc);
        hv.y = pk_bf16((float)acc[mf][nf][2] * sc, (float)acc[mf][nf][3] * sc);
        const size_t base = ((size_t)((tok0 >> 10) * HEADS + hh) << 16)
                          + ((size_t)dd << 10) + (tok0 & 1023);
        *(uint2*)(vtp + base) = hv;
      }
    }
  }
}

// ---------- flash attention: KVBLK=128, 4 static sub-phases, in-register P ----------
__global__ __launch_bounds__(512) void attn_mfma(
    const u16* __restrict__ qp, const u16* __restrict__ kp, const u16* __restrict__ vtp,
    u16* __restrict__ ohp)
{
  // per buffer (32KB): K 16K (128 rows x 128B) | V half0 8K | V half1 8K ; two buffers
  __shared__ __align__(16) char lds[65536];
  const int t = threadIdx.x, w = t >> 6, l = t & 63;
  const int l31 = l & 31, h = l >> 5;
  const int id = blockIdx.x;
  const int bh = ((id & 7) << 4) + ((id >> 3) & 15);   // q-blocks of a bh share an XCD
  const int qbase = ((id >> 7) << 8) + (w << 5);       // 256 q-rows per block, 32 per wave
  const size_t bhoff = (size_t)bh << 16;

  // Q B-frags: B[col=q=l31][k=ks*16+h*8+e], q pre-scaled by 0.125*log2e
  FragU qf[4];
#pragma unroll
  for (int ks = 0; ks < 4; ++ks)
    qf[ks].u = *(const uint4*)(qp + bhoff + ((size_t)(qbase + l31) << 6) + (ks << 4) + (h << 3));

  f32x16 oacc[2];
  oacc[0] = 0.f; oacc[1] = 0.f;
  float lpart = 0.f;

  stage_rows<2, 512>((const char*)(kp + bhoff), 128, lds, t);
  stage_rows<1, 512>((const char*)(vtp + bhoff), 2048, lds + 16384, t);
  stage_rows<1, 512>((const char*)(vtp + bhoff + 64), 2048, lds + 24576, t);
  __syncthreads();

  for (int kb = 0; kb < 8; ++kb) {
    char* cur = lds + ((kb & 1) << 15);
    if (kb < 7) {
      char* nxt = lds + (((kb + 1) & 1) << 15);
      const size_t kn = kb + 1;
      stage_rows<2, 512>((const char*)(kp + bhoff + (kn << 13)), 128, nxt, t);
      stage_rows<1, 512>((const char*)(vtp + bhoff + (kn << 7)), 2048, nxt + 16384, t);
      stage_rows<1, 512>((const char*)(vtp + bhoff + (kn << 7) + 64), 2048, nxt + 24576, t);
    }

    // four 32-key sub-phases: QK -> exp2/pack -> permlane -> PV
#pragma unroll
    for (int sub = 0; sub < 4; ++sub) {
      f32x16 s = 0.f;
#pragma unroll
      for (int ks = 0; ks < 4; ++ks) {
        FragU kf;
        kf.u = ld_chunk(cur, (sub << 5) + l31, (ks << 1) + h);
        __builtin_amdgcn_s_setprio(1);
        s = mfma32(kf, qf[ks], s);
        __builtin_amdgcn_s_setprio(0);
      }

      u32 W[8];
      float lsum = 0.f;
#pragma unroll
      for (int j = 0; j < 8; ++j) {
        const float a = __builtin_amdgcn_exp2f(s[2 * j]);
        const float b = __builtin_amdgcn_exp2f(s[2 * j + 1]);
        lsum += a + b;
        W[j] = pk_bf16(a, b);
      }
      lpart += lsum;

      FragU pf[2];
#pragma unroll
      for (int kk = 0; kk < 2; ++kk) {
        u32 a0 = W[4 * kk + 0], b0 = W[4 * kk + 2];
        u32 a1 = W[4 * kk + 1], b1 = W[4 * kk + 3];
        pl32swap(a0, b0); pl32swap(a1, b1);
        pf[kk].u = make_uint4(a0, a1, b0, b1);
      }

      char* Vh = cur + 16384 + ((sub >> 1) << 13);
#pragma unroll
      for (int ks = 0; ks < 2; ++ks)
#pragma unroll
        for (int dt = 0; dt < 2; ++dt) {
          FragU vf;
          vf.u = ld_chunk(Vh, (dt << 5) + l31, ((sub & 1) << 2) + (ks << 1) + h);
          __builtin_amdgcn_s_setprio(1);
          oacc[dt] = mfma32(vf, pf[ks], oacc[dt]);
          __builtin_amdgcn_s_setprio(0);
        }
    }
    __syncthreads();   // buffer swap; drains prefetch (had the whole compute phase)
  }

  lpart += __shfl_xor(lpart, 32, 64);
  const float invl = 1.0f / lpart;

  const int b = bh >> 4, hd_ = bh & 15;
  const size_t orow = (size_t)b * NN + qbase + l31;
  u16* ohb = ohp + (orow << 10) + (hd_ << 6);
#pragma unroll
  for (int dt = 0; dt < 2; ++dt)
#pragma unroll
    for (int rg = 0; rg < 4; ++rg) {
      const int d0 = (dt << 5) + (rg << 3) + (h << 2);
      const float v0 = oacc[dt][4 * rg + 0] * invl, v1 = oacc[dt][4 * rg + 1] * invl;
      const float v2 = oacc[dt][4 * rg + 2] * invl, v3 = oacc[dt][4 * rg + 3] * invl;
      uint2 hv;
      hv.x = (u32)f2bf(v0) | ((u32)f2bf(v1) << 16);
      hv.y = (u32)f2bf(v2) | ((u32)f2bf(v3) << 16);
      *(uint2*)(ohb + d0) = hv;
    }
}

// ---------- out projection: o(bf16) x W_codes(bf16), + bias ----------
__global__ __launch_bounds__(256) void gemm_out_mfma(const u16* __restrict__ Ah,
    const u16* __restrict__ B, const unsigned* __restrict__ scal,
    const float* __restrict__ bias, float* __restrict__ out)
{
  __shared__ __align__(16) char lds[32768];
  char* Ahs = lds;
  char* Bs  = lds + 16384;
  const int t = threadIdx.x, w = t >> 6, l = t & 63;
  const int lg = l >> 4, lc = l & 15;
  const int wm = (w >> 1) << 6, wn = (w & 1) << 6;
  f32x4 acc[4][4];
#pragma unroll
  for (int i = 0; i < 4; ++i)
#pragma unroll
    for (int j = 0; j < 4; ++j) acc[i][j] = 0.f;

  const char* gAh = (const char*)Ah + ((size_t)blockIdx.y << 7) * 2048;
  const char* gB  = (const char*)B  + ((size_t)blockIdx.x << 7) * 2048;

  for (int k0 = 0; k0 < KDIM; k0 += 64) {
    stage_rows<4, 256>(gAh + k0 * 2, 2048, Ahs, t);
    stage_rows<4, 256>(gB  + k0 * 2, 2048, Bs,  t);
    __syncthreads();
#pragma unroll
    for (int ks = 0; ks < 2; ++ks) {
      FragU a[4], b[4];
#pragma unroll
      for (int mf = 0; mf < 4; ++mf) a[mf].u = ld_chunk(Ahs, wm + (mf << 4) + lc, (ks << 2) + lg);
#pragma unroll
      for (int nf = 0; nf < 4; ++nf) b[nf].u = ld_chunk(Bs, wn + (nf << 4) + lc, (ks << 2) + lg);
      __builtin_amdgcn_s_setprio(1);
#pragma unroll
      for (int mf = 0; mf < 4; ++mf)
#pragma unroll
        for (int nf = 0; nf < 4; ++nf) acc[mf][nf] = mfma16(a[mf], b[nf], acc[mf][nf]);
      __builtin_amdgcn_s_setprio(0);
    }
    __syncthreads();
  }

  const float sc = __uint_as_float(scal[2]) / 127.0f;
  const int cb = ((int)blockIdx.x << 7) + wn;
  const int mb = ((int)blockIdx.y << 7) + wm;
#pragma unroll
  for (int nf = 0; nf < 4; ++nf) {
    const int col = cb + (nf << 4) + lc;
    const float bv = bias[col];
#pragma unroll
    for (int mf = 0; mf < 4; ++mf)
#pragma unroll
      for (int r = 0; r < 4; ++r) {
        const int row = mb + (mf << 4) + (lg << 2) + r;
        out[(size_t)row * NC + col] = acc[mf][nf][r] * sc + bv;
      }
  }
}

__global__ void ws_fail_kernel(float* out) { out[0] = 1.0e6f; }

// ---------- launcher ----------
extern "C" void kernel_launch(void* const* d_in, const int* in_sizes, int n_in,
                              void* d_out, int out_size, void* d_ws, size_t ws_size,
                              hipStream_t stream) {
  const float* x     = (const float*)d_in[0];
  const float* gamma = (const float*)d_in[1];
  const float* beta  = (const float*)d_in[2];
  const float* Wqkv  = (const float*)d_in[3];
  const float* Wout  = (const float*)d_in[4];
  const float* bout  = (const float*)d_in[5];
  float* out = (float*)d_out;

  char* ws = (char*)d_ws;
  unsigned* scal = (unsigned*)ws;          // [0]=s_act [1]=s_wqkv [2]=s_wout
  size_t off = 256;
  float* actp = (float*)(ws + off); off += 2048 * 4;
  float* wqp  = (float*)(ws + off); off += 512 * 4;
  float* wop  = (float*)(ws + off); off += 256 * 4;
  off = (off + 255) & ~(size_t)255;
  float2* mrs = (float2*)(ws + off); off += (size_t)M_TOT * 8;
  char* xq  = ws + off; off += (size_t)M_TOT * KDIM;       // i8 codes
  char* wqi = ws + off; off += (size_t)O_QKV * KDIM;       // i8 codes
  u16* woi = (u16*)(ws + off); off += (size_t)NC * KDIM * 2;  // bf16 codes
  u16* qb  = (u16*)(ws + off); off += 16777216;
  u16* kb  = (u16*)(ws + off); off += 16777216;
  u16* vtb = (u16*)(ws + off); off += 16777216;
  u16* oh  = (u16*)(ws + off); off += 16777216;
  if (ws_size < off) { ws_fail_kernel<<<1, 1, 0, stream>>>(out); return; }

  prep_kernel<<<2816, 256, 0, stream>>>(x, gamma, beta, (const float4*)Wqkv,
                                        (const float4*)Wout, mrs, actp, wqp, wop);
  reduce3<<<1, 256, 0, stream>>>(actp, wqp, wop, scal);
  quant_all<<<9216, 256, 0, stream>>>(x, gamma, beta, mrs, scal, (u32*)xq,
                                      (const float4*)Wqkv, (u32*)wqi,
                                      (const float4*)Wout, (uint2*)woi);

  dim3 g1(O_QKV / 128, M_TOT / 128);
  gemm_qkv_mfma<<<g1, 256, 0, stream>>>(xq, wqi, scal, qb, kb, vtb);

  attn_mfma<<<512, 512, 0, stream>>>(qb, kb, vtb, oh);

  dim3 g3(NC / 128, M_TOT / 128);
  gemm_out_mfma<<<g3, 256, 0, stream>>>(oh, woi, scal, bout, out);
}

// Round 14
// 137.558 us; speedup vs baseline: 1.1339x; 1.0115x over previous
//
#include <hip/hip_runtime.h>
#include <hip/hip_bf16.h>
#include <math.h>

typedef unsigned int u32;
typedef unsigned short u16;
using f32x4  = __attribute__((ext_vector_type(4))) float;
using f32x16 = __attribute__((ext_vector_type(16))) float;
using bfrag  = __attribute__((ext_vector_type(8))) short;
using i32x4  = __attribute__((ext_vector_type(4))) int;
union FragU { uint4 u; bfrag f; };
union FragI { uint4 u; i32x4 f; };

#define HEADS 16
#define DH    64
#define NB    8
#define NN    1024
#define NC    1024
#define M_TOT 8192
#define O_QKV 3072
#define KDIM  1024
#define LOG2E 1.44269504088896340736f

// ---------- small helpers ----------
static __device__ __forceinline__ u16 f2bf(float f) {          // RNE float->bf16
  u32 u = __float_as_uint(f);
  return (u16)((u + 0x7fffu + ((u >> 16) & 1u)) >> 16);
}
static __device__ __forceinline__ u32 pk_bf16(float a, float b) {  // packed RNE pair
  __hip_bfloat162 h = __float22bfloat162_rn(make_float2(a, b));
  u32 r; __builtin_memcpy(&r, &h, 4); return r;
}

static __device__ __forceinline__ float wave_sum(float v) {
#pragma unroll
  for (int off = 32; off > 0; off >>= 1) v += __shfl_xor(v, off, 64);
  return v;
}
static __device__ __forceinline__ float wave_max(float v) {
#pragma unroll
  for (int off = 32; off > 0; off >>= 1) v = fmaxf(v, __shfl_xor(v, off, 64));
  return v;
}

static __device__ __forceinline__ f32x4 mfma16(FragU a, FragU b, f32x4 c) {
  return __builtin_amdgcn_mfma_f32_16x16x32_bf16(a.f, b.f, c, 0, 0, 0);
}
static __device__ __forceinline__ f32x16 mfma32(FragU a, FragU b, f32x16 c) {
  return __builtin_amdgcn_mfma_f32_32x32x16_bf16(a.f, b.f, c, 0, 0, 0);
}
static __device__ __forceinline__ i32x4 mfma16i(FragI a, FragI b, i32x4 c) {
  return __builtin_amdgcn_mfma_i32_16x16x64_i8(a.f, b.f, c, 0, 0, 0);
}

// half-exchange: a' = dest-half-selected {a,b} from lanes 0-31; b' = same from lanes 32-63
static __device__ __forceinline__ void pl32swap(u32& a, u32& b) {
#if __has_builtin(__builtin_amdgcn_permlane32_swap)
  using u32x2 = __attribute__((ext_vector_type(2))) unsigned int;
  u32x2 r = __builtin_amdgcn_permlane32_swap(a, b, false, false);
  a = r[0]; b = r[1];
#else
  asm volatile("v_permlane32_swap_b32 %0, %1" : "+v"(a), "+v"(b));
#endif
}

// Stage (P*BLK/8) rows x 128B per row: linear LDS dest, XOR-swizzled global source.
// Logical LDS slot [row][kc] holds G[row][kc ^ (row&7)]  (16B chunks, 8/row).
template<int P, int BLK>
static __device__ __forceinline__ void stage_rows(const char* g, int row_stride,
                                                  char* ldsb, int t) {
#pragma unroll
  for (int p = 0; p < P; ++p) {
    const int c = p * BLK + t;
    const int row = c >> 3, kc = c & 7;
    const char* gp = g + (size_t)row * row_stride + ((kc ^ (row & 7)) << 4);
    char* lp = ldsb + ((p * BLK + (t & ~63)) << 4);
    __builtin_amdgcn_global_load_lds((const __attribute__((address_space(1))) void*)gp,
                                     (__attribute__((address_space(3))) void*)lp, 16, 0, 0);
  }
}
// read logical [row][chunk] (chunk = 16B), applying the same XOR
static __device__ __forceinline__ uint4 ld_chunk(const char* base, int row, int chunk) {
  return *(const uint4*)(base + (((row << 3) + (chunk ^ (row & 7))) << 4));
}

// ---------- fused prep: LN stats (blocks 0..2047) + weight absmax partials ----------
__global__ __launch_bounds__(256) void prep_kernel(const float* __restrict__ x,
    const float* __restrict__ g, const float* __restrict__ b,
    const float4* __restrict__ wq, const float4* __restrict__ wo,
    float2* __restrict__ mrs, float* __restrict__ actp,
    float* __restrict__ wqp, float* __restrict__ wop)
{
  __shared__ float red[4];
  const int bid = blockIdx.x, t = threadIdx.x;
  if (bid < 2048) {                                    // LayerNorm stats, wave-per-row
    const int w = t >> 6, l = t & 63;
    const int row = (bid << 2) + w;
    const float4* xr = (const float4*)(x + (size_t)row * NC);
    float4 v[4];
#pragma unroll
    for (int j = 0; j < 4; ++j) v[j] = xr[l + (j << 6)];
    float s = 0.f;
#pragma unroll
    for (int j = 0; j < 4; ++j) s += (v[j].x + v[j].y) + (v[j].z + v[j].w);
    s = wave_sum(s);
    const float mu = s * (1.0f / NC);
    float ss = 0.f;
#pragma unroll
    for (int j = 0; j < 4; ++j) {
      const float dx = v[j].x - mu, dy = v[j].y - mu, dz = v[j].z - mu, dw = v[j].w - mu;
      ss += (dx * dx + dy * dy) + (dz * dz + dw * dw);
    }
    ss = wave_sum(ss);
    const float rstd = 1.0f / sqrtf(ss * (1.0f / NC) + 1e-5f);
    if (l == 0) mrs[row] = make_float2(mu, rstd);
    float am = 0.f;
#pragma unroll
    for (int j = 0; j < 4; ++j) {
      const float4 gv = ((const float4*)g)[l + (j << 6)];
      const float4 bv = ((const float4*)b)[l + (j << 6)];
      const float yx = (v[j].x - mu) * rstd * gv.x + bv.x;
      const float yy = (v[j].y - mu) * rstd * gv.y + bv.y;
      const float yz = (v[j].z - mu) * rstd * gv.z + bv.z;
      const float yw = (v[j].w - mu) * rstd * gv.w + bv.w;
      am = fmaxf(am, fmaxf(fmaxf(fabsf(yx), fabsf(yy)), fmaxf(fabsf(yz), fabsf(yw))));
    }
    am = wave_max(am);
    if (l == 0) red[w] = am;
    __syncthreads();
    if (t == 0) actp[bid] = fmaxf(fmaxf(red[0], red[1]), fmaxf(red[2], red[3]));
  } else {                                             // weight absmax partials
    const float4* p; int n4, lb, nb; float* o;
    if (bid < 2560) { p = wq; n4 = O_QKV * KDIM / 4; lb = bid - 2048; nb = 512; o = wqp + lb; }
    else            { p = wo; n4 = NC * KDIM / 4;    lb = bid - 2560; nb = 256; o = wop + lb; }
    float m = 0.f;
    for (int i = lb * 256 + t; i < n4; i += nb * 256) {
      float4 v = p[i];
      m = fmaxf(m, fmaxf(fmaxf(fabsf(v.x), fabsf(v.y)), fmaxf(fabsf(v.z), fabsf(v.w))));
    }
    m = wave_max(m);
    if ((t & 63) == 0) red[t >> 6] = m;
    __syncthreads();
    if (t == 0) *o = fmaxf(fmaxf(red[0], red[1]), fmaxf(red[2], red[3]));
  }
}

// ---------- final scalar reduce: 3 partial arrays -> scal[0..2] ----------
__global__ __launch_bounds__(256) void reduce3(const float* __restrict__ actp,
    const float* __restrict__ wqp, const float* __restrict__ wop,
    unsigned* __restrict__ scal)
{
  const int t = threadIdx.x;
  float a = 0.f, q = 0.f, o = 0.f;
#pragma unroll
  for (int k = 0; k < 8; ++k) a = fmaxf(a, actp[t + (k << 8)]);
  q = fmaxf(wqp[t], wqp[t + 256]);
  o = wop[t];
  a = wave_max(a); q = wave_max(q); o = wave_max(o);
  __shared__ float ra[4], rq[4], ro[4];
  if ((t & 63) == 0) { ra[t >> 6] = a; rq[t >> 6] = q; ro[t >> 6] = o; }
  __syncthreads();
  if (t == 0) {
    a = fmaxf(fmaxf(ra[0], ra[1]), fmaxf(ra[2], ra[3]));
    q = fmaxf(fmaxf(rq[0], rq[1]), fmaxf(rq[2], rq[3]));
    o = fmaxf(fmaxf(ro[0], ro[1]), fmaxf(ro[2], ro[3]));
    scal[0] = __float_as_uint(a == 0.f ? 1.f : a);
    scal[1] = __float_as_uint(q == 0.f ? 1.f : q);
    scal[2] = __float_as_uint(o == 0.f ? 1.f : o);
  }
}

// ---------- fused quant: x->i8 (blocks 0..8191), Wqkv->i8, Wout->bf16 ----------
__global__ __launch_bounds__(256) void quant_all(const float* __restrict__ x,
    const float* __restrict__ g, const float* __restrict__ b,
    const float2* __restrict__ mrs, const unsigned* __restrict__ scal,
    u32* __restrict__ xq, const float4* __restrict__ wq, u32* __restrict__ oq,
    const float4* __restrict__ wo, uint2* __restrict__ oo)
{
  const int bid = blockIdx.x, t = threadIdx.x;
  if (bid < 8192) {
    const long long row = bid;
    const float2 ms = mrs[row];
    const float s = __uint_as_float(scal[0]);
    const float4 v = ((const float4*)(x + row * NC))[t];
    const float4 gv = ((const float4*)g)[t];
    const float4 bv = ((const float4*)b)[t];
    float4 y;                                  // identical op sequence to prep -> same y
    y.x = (v.x - ms.x) * ms.y * gv.x + bv.x;
    y.y = (v.y - ms.x) * ms.y * gv.y + bv.y;
    y.z = (v.z - ms.x) * ms.y * gv.z + bv.z;
    y.w = (v.w - ms.x) * ms.y * gv.w + bv.w;
    const int ia = (int)rintf(y.x / s * 127.0f);   // reference op order: x / s * 127
    const int ib = (int)rintf(y.y / s * 127.0f);
    const int ic = (int)rintf(y.z / s * 127.0f);
    const int id = (int)rintf(y.w / s * 127.0f);
    xq[row * 256 + t] = (u32)(ia & 255) | ((u32)(ib & 255) << 8)
                      | ((u32)(ic & 255) << 16) | ((u32)(id & 255) << 24);
  } else if (bid < 8960) {
    const float s = __uint_as_float(scal[1]);
    const int base = (bid - 8192) << 10;
#pragma unroll
    for (int k = 0; k < 4; ++k) {
      const int i = base + (k << 8) + t;
      float4 v = wq[i];
      const int ia = (int)rintf(v.x / s * 127.0f);
      const int ib = (int)rintf(v.y / s * 127.0f);
      const int ic = (int)rintf(v.z / s * 127.0f);
      const int id = (int)rintf(v.w / s * 127.0f);
      oq[i] = (u32)(ia & 255) | ((u32)(ib & 255) << 8)
            | ((u32)(ic & 255) << 16) | ((u32)(id & 255) << 24);
    }
  } else {
    const float s = __uint_as_float(scal[2]);
    const int base = (bid - 8960) << 10;
#pragma unroll
    for (int k = 0; k < 4; ++k) {
      const int i = base + (k << 8) + t;
      float4 v = wo[i];
      uint2 o;
      o.x = pk_bf16(rintf(v.x / s * 127.0f), rintf(v.y / s * 127.0f));
      o.y = pk_bf16(rintf(v.z / s * 127.0f), rintf(v.w / s * 127.0f));
      oo[i] = o;
    }
  }
}

// ---------- QKV GEMM: int8 MFMA (exact), XCD-chunked 1D grid (1536 blocks) ----------
// Each XCD owns 192 consecutive lids = 8 full M-strips: A read once per strip,
// whole B (3MB) cycles inside the XCD's 4MB L2.
__global__ __launch_bounds__(256) void gemm_qkv_mfma(const char* __restrict__ A,
    const char* __restrict__ B, const unsigned* __restrict__ scal,
    u16* __restrict__ qp, u16* __restrict__ kp, u16* __restrict__ vtp)
{
  __shared__ __align__(16) char lds[32768];
  char* As = lds;                    // 128 rows x 128 i8 (one K-tile of 128)
  char* Bs = lds + 16384;
  const int t = threadIdx.x, w = t >> 6, l = t & 63;
  const int lg = l >> 4, lc = l & 15;
  const int wm = (w >> 1) << 6, wn = (w & 1) << 6;

  const int lid = ((blockIdx.x & 7) * 192) + (blockIdx.x >> 3);   // bijective: 1536 % 8 == 0
  const int bx = lid % 24;                                        // N-tile
  const int by = lid / 24;                                        // M-tile

  i32x4 acc[4][4];
#pragma unroll
  for (int i = 0; i < 4; ++i)
#pragma unroll
    for (int j = 0; j < 4; ++j) acc[i][j] = 0;

  const char* gA = A + ((size_t)by << 7) * KDIM;
  const char* gB = B + ((size_t)bx << 7) * KDIM;

  for (int k0 = 0; k0 < KDIM; k0 += 128) {           // 8 K-tiles
    stage_rows<4, 256>(gA + k0, KDIM, As, t);
    stage_rows<4, 256>(gB + k0, KDIM, Bs, t);
    __syncthreads();
#pragma unroll
    for (int ks = 0; ks < 2; ++ks) {                 // K=64 per MFMA
      FragI a[4], b[4];
#pragma unroll
      for (int mf = 0; mf < 4; ++mf) a[mf].u = ld_chunk(As, wm + (mf << 4) + lc, (ks << 2) + lg);
#pragma unroll
      for (int nf = 0; nf < 4; ++nf) b[nf].u = ld_chunk(Bs, wn + (nf << 4) + lc, (ks << 2) + lg);
      __builtin_amdgcn_s_setprio(1);
#pragma unroll
      for (int mf = 0; mf < 4; ++mf)
#pragma unroll
        for (int nf = 0; nf < 4; ++nf) acc[mf][nf] = mfma16i(a[mf], b[nf], acc[mf][nf]);
      __builtin_amdgcn_s_setprio(0);
    }
    __syncthreads();
  }

  const float sa = __uint_as_float(scal[0]), sw = __uint_as_float(scal[1]);
  const int which = bx >> 3;                         // 0=q 1=k 2=v
  float sc = sa * sw / 16129.0f;
  if (which == 0) sc *= 0.125f * LOG2E;              // fold Dh^-0.5 AND log2(e) into q
  const int obase = ((bx & 7) << 7) + wn;
  const int mbase = (by << 7) + wm;

  if (which < 2) {
    u16* d_ = which ? kp : qp;
#pragma unroll
    for (int nf = 0; nf < 4; ++nf) {
      const int od = obase + (nf << 4) + lc;
      const int hh = od >> 6, dd = od & 63;
#pragma unroll
      for (int mf = 0; mf < 4; ++mf)
#pragma unroll
        for (int r = 0; r < 4; ++r) {
          const int tok = mbase + (mf << 4) + (lg << 2) + r;
          const size_t addr = ((size_t)((tok >> 10) * HEADS + hh) << 16)
                            + ((size_t)(tok & 1023) << 6) + dd;
          d_[addr] = f2bf((float)acc[mf][nf][r] * sc);
        }
    }
  } else {
#pragma unroll
    for (int nf = 0; nf < 4; ++nf) {
      const int od = obase + (nf << 4) + lc;
      const int hh = od >> 6, dd = od & 63;
#pragma unroll
      for (int mf = 0; mf < 4; ++mf) {
        const int tok0 = mbase + (mf << 4) + (lg << 2);
        uint2 hv;
        hv.x = pk_bf16((float)acc[mf][nf][0] * sc, (float)acc[mf][nf][1] * sc);
        hv.y = pk_bf16((float)acc[mf][nf][2] * sc, (float)acc[mf][nf][3] * sc);
        const size_t base = ((size_t)((tok0 >> 10) * HEADS + hh) << 16)
                          + ((size_t)dd << 10) + (tok0 & 1023);
        *(uint2*)(vtp + base) = hv;
      }
    }
  }
}

// ---------- flash attention: KVBLK=128, 4 static sub-phases, in-register P ----------
__global__ __launch_bounds__(512) void attn_mfma(
    const u16* __restrict__ qp, const u16* __restrict__ kp, const u16* __restrict__ vtp,
    u16* __restrict__ ohp)
{
  // per buffer (32KB): K 16K (128 rows x 128B) | V half0 8K | V half1 8K ; two buffers
  __shared__ __align__(16) char lds[65536];
  const int t = threadIdx.x, w = t >> 6, l = t & 63;
  const int l31 = l & 31, h = l >> 5;
  const int id = blockIdx.x;
  const int bh = ((id & 7) << 4) + ((id >> 3) & 15);   // q-blocks of a bh share an XCD
  const int qbase = ((id >> 7) << 8) + (w << 5);       // 256 q-rows per block, 32 per wave
  const size_t bhoff = (size_t)bh << 16;

  // Q B-frags: B[col=q=l31][k=ks*16+h*8+e], q pre-scaled by 0.125*log2e
  FragU qf[4];
#pragma unroll
  for (int ks = 0; ks < 4; ++ks)
    qf[ks].u = *(const uint4*)(qp + bhoff + ((size_t)(qbase + l31) << 6) + (ks << 4) + (h << 3));

  f32x16 oacc[2];
  oacc[0] = 0.f; oacc[1] = 0.f;
  float lpart = 0.f;

  stage_rows<2, 512>((const char*)(kp + bhoff), 128, lds, t);
  stage_rows<1, 512>((const char*)(vtp + bhoff), 2048, lds + 16384, t);
  stage_rows<1, 512>((const char*)(vtp + bhoff + 64), 2048, lds + 24576, t);
  __syncthreads();

  for (int kb = 0; kb < 8; ++kb) {
    char* cur = lds + ((kb & 1) << 15);
    if (kb < 7) {
      char* nxt = lds + (((kb + 1) & 1) << 15);
      const size_t kn = kb + 1;
      stage_rows<2, 512>((const char*)(kp + bhoff + (kn << 13)), 128, nxt, t);
      stage_rows<1, 512>((const char*)(vtp + bhoff + (kn << 7)), 2048, nxt + 16384, t);
      stage_rows<1, 512>((const char*)(vtp + bhoff + (kn << 7) + 64), 2048, nxt + 24576, t);
    }

    // four 32-key sub-phases: QK -> exp2/pack -> permlane -> PV
#pragma unroll
    for (int sub = 0; sub < 4; ++sub) {
      f32x16 s = 0.f;
#pragma unroll
      for (int ks = 0; ks < 4; ++ks) {
        FragU kf;
        kf.u = ld_chunk(cur, (sub << 5) + l31, (ks << 1) + h);
        __builtin_amdgcn_s_setprio(1);
        s = mfma32(kf, qf[ks], s);
        __builtin_amdgcn_s_setprio(0);
      }

      u32 W[8];
      float lsum = 0.f;
#pragma unroll
      for (int j = 0; j < 8; ++j) {
        const float a = __builtin_amdgcn_exp2f(s[2 * j]);
        const float b = __builtin_amdgcn_exp2f(s[2 * j + 1]);
        lsum += a + b;
        W[j] = pk_bf16(a, b);
      }
      lpart += lsum;

      FragU pf[2];
#pragma unroll
      for (int kk = 0; kk < 2; ++kk) {
        u32 a0 = W[4 * kk + 0], b0 = W[4 * kk + 2];
        u32 a1 = W[4 * kk + 1], b1 = W[4 * kk + 3];
        pl32swap(a0, b0); pl32swap(a1, b1);
        pf[kk].u = make_uint4(a0, a1, b0, b1);
      }

      char* Vh = cur + 16384 + ((sub >> 1) << 13);
#pragma unroll
      for (int ks = 0; ks < 2; ++ks)
#pragma unroll
        for (int dt = 0; dt < 2; ++dt) {
          FragU vf;
          vf.u = ld_chunk(Vh, (dt << 5) + l31, ((sub & 1) << 2) + (ks << 1) + h);
          __builtin_amdgcn_s_setprio(1);
          oacc[dt] = mfma32(vf, pf[ks], oacc[dt]);
          __builtin_amdgcn_s_setprio(0);
        }
    }
    __syncthreads();   // buffer swap; drains prefetch (had the whole compute phase)
  }

  lpart += __shfl_xor(lpart, 32, 64);
  const float invl = 1.0f / lpart;

  const int b = bh >> 4, hd_ = bh & 15;
  const size_t orow = (size_t)b * NN + qbase + l31;
  u16* ohb = ohp + (orow << 10) + (hd_ << 6);
#pragma unroll
  for (int dt = 0; dt < 2; ++dt)
#pragma unroll
    for (int rg = 0; rg < 4; ++rg) {
      const int d0 = (dt << 5) + (rg << 3) + (h << 2);
      const float v0 = oacc[dt][4 * rg + 0] * invl, v1 = oacc[dt][4 * rg + 1] * invl;
      const float v2 = oacc[dt][4 * rg + 2] * invl, v3 = oacc[dt][4 * rg + 3] * invl;
      uint2 hv;
      hv.x = (u32)f2bf(v0) | ((u32)f2bf(v1) << 16);
      hv.y = (u32)f2bf(v2) | ((u32)f2bf(v3) << 16);
      *(uint2*)(ohb + d0) = hv;
    }
}

// ---------- out projection: o(bf16) x W_codes(bf16), XCD-chunked 1D grid (512) ----------
__global__ __launch_bounds__(256) void gemm_out_mfma(const u16* __restrict__ Ah,
    const u16* __restrict__ B, const unsigned* __restrict__ scal,
    const float* __restrict__ bias, float* __restrict__ out)
{
  __shared__ __align__(16) char lds[32768];
  char* Ahs = lds;
  char* Bs  = lds + 16384;
  const int t = threadIdx.x, w = t >> 6, l = t & 63;
  const int lg = l >> 4, lc = l & 15;
  const int wm = (w >> 1) << 6, wn = (w & 1) << 6;

  const int lid = ((blockIdx.x & 7) << 6) + (blockIdx.x >> 3);    // bijective: 512 % 8 == 0
  const int bx = lid & 7;                                         // N-tile
  const int by = lid >> 3;                                        // M-tile

  f32x4 acc[4][4];
#pragma unroll
  for (int i = 0; i < 4; ++i)
#pragma unroll
    for (int j = 0; j < 4; ++j) acc[i][j] = 0.f;

  const char* gAh = (const char*)Ah + ((size_t)by << 7) * 2048;
  const char* gB  = (const char*)B  + ((size_t)bx << 7) * 2048;

  for (int k0 = 0; k0 < KDIM; k0 += 64) {
    stage_rows<4, 256>(gAh + k0 * 2, 2048, Ahs, t);
    stage_rows<4, 256>(gB  + k0 * 2, 2048, Bs,  t);
    __syncthreads();
#pragma unroll
    for (int ks = 0; ks < 2; ++ks) {
      FragU a[4], b[4];
#pragma unroll
      for (int mf = 0; mf < 4; ++mf) a[mf].u = ld_chunk(Ahs, wm + (mf << 4) + lc, (ks << 2) + lg);
#pragma unroll
      for (int nf = 0; nf < 4; ++nf) b[nf].u = ld_chunk(Bs, wn + (nf << 4) + lc, (ks << 2) + lg);
      __builtin_amdgcn_s_setprio(1);
#pragma unroll
      for (int mf = 0; mf < 4; ++mf)
#pragma unroll
        for (int nf = 0; nf < 4; ++nf) acc[mf][nf] = mfma16(a[mf], b[nf], acc[mf][nf]);
      __builtin_amdgcn_s_setprio(0);
    }
    __syncthreads();
  }

  const float sc = __uint_as_float(scal[2]) / 127.0f;
  const int cb = (bx << 7) + wn;
  const int mb = (by << 7) + wm;
#pragma unroll
  for (int nf = 0; nf < 4; ++nf) {
    const int col = cb + (nf << 4) + lc;
    const float bv = bias[col];
#pragma unroll
    for (int mf = 0; mf < 4; ++mf)
#pragma unroll
      for (int r = 0; r < 4; ++r) {
        const int row = mb + (mf << 4) + (lg << 2) + r;
        out[(size_t)row * NC + col] = acc[mf][nf][r] * sc + bv;
      }
  }
}

__global__ void ws_fail_kernel(float* out) { out[0] = 1.0e6f; }

// ---------- launcher ----------
extern "C" void kernel_launch(void* const* d_in, const int* in_sizes, int n_in,
                              void* d_out, int out_size, void* d_ws, size_t ws_size,
                              hipStream_t stream) {
  const float* x     = (const float*)d_in[0];
  const float* gamma = (const float*)d_in[1];
  const float* beta  = (const float*)d_in[2];
  const float* Wqkv  = (const float*)d_in[3];
  const float* Wout  = (const float*)d_in[4];
  const float* bout  = (const float*)d_in[5];
  float* out = (float*)d_out;

  char* ws = (char*)d_ws;
  unsigned* scal = (unsigned*)ws;          // [0]=s_act [1]=s_wqkv [2]=s_wout
  size_t off = 256;
  float* actp = (float*)(ws + off); off += 2048 * 4;
  float* wqp  = (float*)(ws + off); off += 512 * 4;
  float* wop  = (float*)(ws + off); off += 256 * 4;
  off = (off + 255) & ~(size_t)255;
  float2* mrs = (float2*)(ws + off); off += (size_t)M_TOT * 8;
  char* xq  = ws + off; off += (size_t)M_TOT * KDIM;       // i8 codes
  char* wqi = ws + off; off += (size_t)O_QKV * KDIM;       // i8 codes
  u16* woi = (u16*)(ws + off); off += (size_t)NC * KDIM * 2;  // bf16 codes
  u16* qb  = (u16*)(ws + off); off += 16777216;
  u16* kb  = (u16*)(ws + off); off += 16777216;
  u16* vtb = (u16*)(ws + off); off += 16777216;
  u16* oh  = (u16*)(ws + off); off += 16777216;
  if (ws_size < off) { ws_fail_kernel<<<1, 1, 0, stream>>>(out); return; }

  prep_kernel<<<2816, 256, 0, stream>>>(x, gamma, beta, (const float4*)Wqkv,
                                        (const float4*)Wout, mrs, actp, wqp, wop);
  reduce3<<<1, 256, 0, stream>>>(actp, wqp, wop, scal);
  quant_all<<<9216, 256, 0, stream>>>(x, gamma, beta, mrs, scal, (u32*)xq,
                                      (const float4*)Wqkv, (u32*)wqi,
                                      (const float4*)Wout, (uint2*)woi);

  gemm_qkv_mfma<<<1536, 256, 0, stream>>>(xq, wqi, scal, qb, kb, vtb);

  attn_mfma<<<512, 512, 0, stream>>>(qb, kb, vtb, oh);

  gemm_out_mfma<<<512, 256, 0, stream>>>(oh, woi, scal, bout, out);
}